// Round 9
// baseline (377.198 us; speedup 1.0000x reference)
//
#include <hip/hip_runtime.h>
#include <hip/hip_bf16.h>

#define N_NODES 50000
#define N_EDGES 500000
#define D 256
#define K_TOT 768      // 3 * D
#define M_TILE 256
#define N_TILE 256
#define BK 32
#define NKT (K_TOT / BK)                     // 24
#define SCAN_N (3 * N_NODES)
#define SCAN_NBLK ((SCAN_N + 1023) / 1024)   // 147
#define NPASS 4                              // dst>>14: 50000 < 4*16384
#define NMB ((N_NODES + M_TILE - 1) / M_TILE)  // 196 blocks, single generation

typedef __attribute__((ext_vector_type(8))) __bf16 bf16x8;
typedef __attribute__((ext_vector_type(4))) float f32x4;

__device__ __forceinline__ unsigned short f2bf(float f) {
    unsigned u = __builtin_bit_cast(unsigned, f);
    u += 0x7FFFu + ((u >> 16) & 1u);   // round-to-nearest-even
    return (unsigned short)(u >> 16);
}
__device__ __forceinline__ float bf2f(unsigned short h) {
    return __builtin_bit_cast(float, (unsigned)h << 16);
}
__device__ __forceinline__ float lo2f(unsigned u) {
    return __builtin_bit_cast(float, u << 16);
}
__device__ __forceinline__ float hi2f(unsigned u) {
    return __builtin_bit_cast(float, u & 0xFFFF0000u);
}
__device__ __forceinline__ void gload16(const unsigned short* g, __bf16* l) {
    __builtin_amdgcn_global_load_lds(
        (const __attribute__((address_space(1))) void*)g,
        (__attribute__((address_space(3))) void*)l, 16, 0, 0);
}

// ---------------- prep: feat->bf16 + W->bf16 transposed + edge COUNT (cnt pre-zeroed) ----------------
__global__ void prep_kernel(const float* __restrict__ feat, unsigned short* __restrict__ fb,
                            const float* __restrict__ W0, const float* __restrict__ W1,
                            const float* __restrict__ W2, unsigned short* __restrict__ WT,
                            const int* __restrict__ d0, const int* __restrict__ d1,
                            const int* __restrict__ d2, int* __restrict__ cnt) {
    int i = blockIdx.x * blockDim.x + threadIdx.x;
    if (i < N_NODES * D / 4) {                       // 3.2M float4 slots
        float4 v = ((const float4*)feat)[i];
        ushort4 pk;
        pk.x = f2bf(v.x); pk.y = f2bf(v.y); pk.z = f2bf(v.z); pk.w = f2bf(v.w);
        ((ushort4*)fb)[i] = pk;
    }
    if (i < D * K_TOT) {                             // WT[c][k], k = r*256+kin
        int c = i / K_TOT;
        int k = i - c * K_TOT;
        int r = k >> 8, kin = k & 255;
        const float* W = (r == 0) ? W0 : (r == 1) ? W1 : W2;
        WT[i] = f2bf(W[kin * D + c]);
    }
    if (i < 3 * N_EDGES) {                           // fused count (cnt zeroed by memset)
        int r = i / N_EDGES;
        int e = i - r * N_EDGES;
        const int* d = (r == 0) ? d0 : (r == 1) ? d1 : d2;
        atomicAdd(&cnt[r * N_NODES + d[e]], 1);
    }
}

// per-block exclusive scan; off/cur hold BLOCK-LOCAL offsets, bsum holds block totals
__global__ void scan1_kernel(const int* __restrict__ cnt, int* __restrict__ off,
                             int* __restrict__ cur, int* __restrict__ bsum) {
    __shared__ int wsum[16];
    int tid = threadIdx.x, lane = tid & 63, wid = tid >> 6;
    int i = blockIdx.x * 1024 + tid;
    int v = (i < SCAN_N) ? cnt[i] : 0;
    int x = v;
    #pragma unroll
    for (int d = 1; d < 64; d <<= 1) {
        int y = __shfl_up(x, d, 64);
        if (lane >= d) x += y;
    }
    if (lane == 63) wsum[wid] = x;
    __syncthreads();
    if (wid == 0 && lane < 16) {
        int s = wsum[lane];
        #pragma unroll
        for (int d = 1; d < 16; d <<= 1) {
            int y = __shfl_up(s, d, 64);
            if (lane >= d) s += y;
        }
        wsum[lane] = s;
    }
    __syncthreads();
    int wpre = wid ? wsum[wid - 1] : 0;
    int excl = x - v + wpre;
    if (i < SCAN_N) { off[i] = excl; cur[i] = excl; }
    if (tid == 1023) bsum[blockIdx.x] = x + wpre;
}

// exclusive scan of the 147 block sums (single block, in place)
__global__ void scan2_kernel(int* __restrict__ bsum) {
    __shared__ int wsum[16];
    int tid = threadIdx.x, lane = tid & 63, wid = tid >> 6;
    int v = (tid < SCAN_NBLK) ? bsum[tid] : 0;
    int x = v;
    #pragma unroll
    for (int d = 1; d < 64; d <<= 1) {
        int y = __shfl_up(x, d, 64);
        if (lane >= d) x += y;
    }
    if (lane == 63) wsum[wid] = x;
    __syncthreads();
    if (wid == 0 && lane < 16) {
        int s = wsum[lane];
        #pragma unroll
        for (int d = 1; d < 16; d <<= 1) {
            int y = __shfl_up(s, d, 64);
            if (lane >= d) s += y;
        }
        wsum[lane] = s;
    }
    __syncthreads();
    int wpre = wid ? wsum[wid - 1] : 0;
    if (tid < SCAN_NBLK) bsum[tid] = x - v + wpre;
}

// fill in NPASS dst-range passes (blockIdx.y = pass): confines the eidx scatter
// to ~2 MB hot window per pass so lines merge in L2 before eviction.
__global__ void fill_kernel(const int* __restrict__ s0, const int* __restrict__ d0,
                            const int* __restrict__ s1, const int* __restrict__ d1,
                            const int* __restrict__ s2, const int* __restrict__ d2,
                            int* __restrict__ cur, const int* __restrict__ bsum,
                            int* __restrict__ eidx) {
    int i = blockIdx.x * blockDim.x + threadIdx.x;
    if (i >= 3 * N_EDGES) return;
    int pass = blockIdx.y;
    int r = i / N_EDGES;
    int e = i - r * N_EDGES;
    const int* d = (r == 0) ? d0 : (r == 1) ? d1 : d2;
    int dd = d[e];
    if ((dd >> 14) != pass) return;
    const int* s = (r == 0) ? s0 : (r == 1) ? s1 : s2;
    int x = r * N_NODES + dd;
    int p = atomicAdd(&cur[x], 1) + bsum[x >> 10];
    eidx[p] = s[e];
}

// ---------------- per-node mean aggregation, all 3 relations per wave ----------------
// Cross-relation interleaved batches: each outer iteration issues 12 paired 16B loads
// (3 relations x 4) before ANY consumption -> ~2 serial memory rounds per wave
// instead of ~6. Lanes 0-31 = even edge of pair, 32-63 = odd; shfl_xor(32) combine.
__global__ void agg_kernel(const unsigned short* __restrict__ fb, const int* __restrict__ off,
                           const int* __restrict__ cnt, const int* __restrict__ bsum,
                           const int* __restrict__ eidx, unsigned short* __restrict__ agg) {
    int n = (blockIdx.x * blockDim.x + threadIdx.x) >> 6;
    int lane = threadIdx.x & 63;
    if (n >= N_NODES) return;
    int half = lane >> 5, sub = lane & 31;
    const unsigned short* fbs = fb + sub * 8;

    int st3[3], dg3[3], e3[3];
    #pragma unroll
    for (int r = 0; r < 3; ++r) {
        int x = r * N_NODES + n;
        st3[r] = off[x] + bsum[x >> 10];
        dg3[r] = cnt[x];
    }
    #pragma unroll
    for (int r = 0; r < 3; ++r)                       // 3 head-loads in flight together
        e3[r] = (lane < min(dg3[r], 64)) ? eidx[st3[r] + lane] : 0;

    float a[3][8];
    #pragma unroll
    for (int r = 0; r < 3; ++r)
        #pragma unroll
        for (int c = 0; c < 8; ++c) a[r][c] = 0.f;

    int dmax = max(max(dg3[0], dg3[1]), dg3[2]);
    int dcap = min(dmax, 64);
    for (int base = 0; base < dcap; base += 8) {
        uint4 vv[3][4];
        #pragma unroll
        for (int r = 0; r < 3; ++r) {                 // issue all 12 loads first
            int deg = min(dg3[r], 64);
            int cl = (deg > 0) ? deg - 1 : 0;
            #pragma unroll
            for (int li = 0; li < 4; ++li) {
                int idx = base + li * 2 + half;
                int sl = (idx < deg) ? idx : cl;      // clamped -> repeat line, L1-hit
                int t = __shfl(e3[r], sl);
                vv[r][li] = *(const uint4*)(fbs + (size_t)t * D);
            }
        }
        #pragma unroll
        for (int r = 0; r < 3; ++r) {                 // then consume
            int deg = min(dg3[r], 64);
            #pragma unroll
            for (int li = 0; li < 4; ++li) {
                int idx = base + li * 2 + half;
                uint4 v = vv[r][li];
                if (idx >= deg) { v.x = 0u; v.y = 0u; v.z = 0u; v.w = 0u; }
                a[r][0] += lo2f(v.x); a[r][1] += hi2f(v.x);
                a[r][2] += lo2f(v.y); a[r][3] += hi2f(v.y);
                a[r][4] += lo2f(v.z); a[r][5] += hi2f(v.z);
                a[r][6] += lo2f(v.w); a[r][7] += hi2f(v.w);
            }
        }
    }
    // safety fallback for deg > 64 (P ~ 0 for Poisson(10), but stay correct)
    #pragma unroll
    for (int r = 0; r < 3; ++r) {
        if (dg3[r] > 64) {
            for (int ei = 64; ei < dg3[r]; ++ei) {
                int t = eidx[st3[r] + ei];
                uint4 v = *(const uint4*)(fbs + (size_t)t * D);
                if (half) { v.x = 0u; v.y = 0u; v.z = 0u; v.w = 0u; }
                a[r][0] += lo2f(v.x); a[r][1] += hi2f(v.x);
                a[r][2] += lo2f(v.y); a[r][3] += hi2f(v.y);
                a[r][4] += lo2f(v.z); a[r][5] += hi2f(v.z);
                a[r][6] += lo2f(v.w); a[r][7] += hi2f(v.w);
            }
        }
    }

    #pragma unroll
    for (int r = 0; r < 3; ++r) {
        int deg = dg3[r];
        float t0 = a[r][0] + __shfl_xor(a[r][0], 32), t1 = a[r][1] + __shfl_xor(a[r][1], 32);
        float t2 = a[r][2] + __shfl_xor(a[r][2], 32), t3 = a[r][3] + __shfl_xor(a[r][3], 32);
        float t4 = a[r][4] + __shfl_xor(a[r][4], 32), t5 = a[r][5] + __shfl_xor(a[r][5], 32);
        float t6 = a[r][6] + __shfl_xor(a[r][6], 32), t7 = a[r][7] + __shfl_xor(a[r][7], 32);
        float sc = (deg > 0) ? 1.0f / (float)deg : 0.0f;
        if (half == 0) {                              // 32 lanes x 16 B = 512 B row
            uint4 pk;
            pk.x = (unsigned)f2bf(t0 * sc) | ((unsigned)f2bf(t1 * sc) << 16);
            pk.y = (unsigned)f2bf(t2 * sc) | ((unsigned)f2bf(t3 * sc) << 16);
            pk.z = (unsigned)f2bf(t4 * sc) | ((unsigned)f2bf(t5 * sc) << 16);
            pk.w = (unsigned)f2bf(t6 * sc) | ((unsigned)f2bf(t7 * sc) << 16);
            *(uint4*)(agg + ((size_t)n * 3 + r) * D + sub * 8) = pk;
        }
    }
}

// ---------------- fused GEMM: out = relu( A[50000][768] @ B[768][256] + masked biases ) ----------------
// SINGLE-GENERATION design: 256x256 tiles, 512 threads (8 waves, 2x4), grid = 196
// blocks < 256 CUs -> all blocks concurrent; per-K-step drain costs amortize.
// 3-buffer LDS (96 KB), unrolled K-loop, counted vmcnt; swizzle seg^((row>>1)&3).
__global__ __launch_bounds__(512) void gemm_kernel(
    const unsigned short* __restrict__ A, const unsigned short* __restrict__ BT,
    const int* __restrict__ cnt,
    const float* __restrict__ b0, const float* __restrict__ b1, const float* __restrict__ b2,
    float* __restrict__ out) {
    __shared__ __bf16 Asl[3][M_TILE][BK];   // 3 x 16 KB
    __shared__ __bf16 Bsl[3][N_TILE][BK];   // 3 x 16 KB
    int tid = threadIdx.x;
    int lane = tid & 63, w = tid >> 6;      // 8 waves
    int wr = w >> 2, wc = w & 3;            // wave tile: 128 rows x 64 cols
    int m0 = blockIdx.x * M_TILE;
    f32x4 acc[8][4] = {};

    // staging geometry: A tile = 1024 16B slots, B tile = 1024; thread does 2+2
    int s_lo = tid;                                      // slot 0..511
    int row_lo = s_lo >> 2, row_hi = (s_lo + 512) >> 2;
    int seg_lo = (s_lo & 3) ^ ((row_lo >> 1) & 3);       // inverse-swizzled global seg
    int seg_hi = (s_lo & 3) ^ ((row_hi >> 1) & 3);
    int gma = m0 + row_lo; if (gma >= N_NODES) gma = N_NODES - 1;
    int gmb = m0 + row_hi; if (gmb >= N_NODES) gmb = N_NODES - 1;
    const unsigned short* ga_lo = A + (size_t)gma * K_TOT + seg_lo * 8;
    const unsigned short* ga_hi = A + (size_t)gmb * K_TOT + seg_hi * 8;
    const unsigned short* gb_lo = BT + (size_t)row_lo * K_TOT + seg_lo * 8;
    const unsigned short* gb_hi = BT + (size_t)row_hi * K_TOT + seg_hi * 8;

    auto stage = [&](int kt, int b) {                    // b compile-time after unroll
        gload16(ga_lo + kt * BK, &Asl[b][0][0] + (size_t)s_lo * 8);
        gload16(ga_hi + kt * BK, &Asl[b][0][0] + (size_t)(s_lo + 512) * 8);
        gload16(gb_lo + kt * BK, &Bsl[b][0][0] + (size_t)s_lo * 8);
        gload16(gb_hi + kt * BK, &Bsl[b][0][0] + (size_t)(s_lo + 512) * 8);
    };

    stage(0, 0);
    stage(1, 1);
    int q = lane >> 4;
    int rr = lane & 15;
    #pragma unroll
    for (int kt = 0; kt < NKT; ++kt) {
        if (kt + 1 < NKT) asm volatile("s_waitcnt vmcnt(4)" ::: "memory");
        else              asm volatile("s_waitcnt vmcnt(0)" ::: "memory");
        __builtin_amdgcn_s_barrier();
        int b = kt % 3;
        bf16x8 af[8], bfr[4];
        #pragma unroll
        for (int mf = 0; mf < 8; ++mf) {
            int row = wr * 128 + mf * 16 + rr;
            af[mf] = *(const bf16x8*)&Asl[b][row][(q ^ ((row >> 1) & 3)) * 8];
        }
        #pragma unroll
        for (int nf = 0; nf < 4; ++nf) {
            int row = wc * 64 + nf * 16 + rr;
            bfr[nf] = *(const bf16x8*)&Bsl[b][row][(q ^ ((row >> 1) & 3)) * 8];
        }
        if (kt + 2 < NKT) stage(kt + 2, (kt + 2) % 3);
        #pragma unroll
        for (int mf = 0; mf < 8; ++mf)
            #pragma unroll
            for (int nf = 0; nf < 4; ++nf)
                acc[mf][nf] = __builtin_amdgcn_mfma_f32_16x16x32_bf16(af[mf], bfr[nf], acc[mf][nf], 0, 0, 0);
    }

    // epilogue: masked biases + relu; C/D layout: col = lane&15, row = (lane>>4)*4 + reg
    #pragma unroll
    for (int mf = 0; mf < 8; ++mf) {
        #pragma unroll
        for (int nf = 0; nf < 4; ++nf) {
            int col = wc * 64 + nf * 16 + rr;            // global col (N_TILE == D)
            #pragma unroll
            for (int reg = 0; reg < 4; ++reg) {
                int row = m0 + wr * 128 + mf * 16 + q * 4 + reg;
                if (row < N_NODES) {
                    float v = acc[mf][nf][reg];
                    if (cnt[row] > 0)               v += b0[col];
                    if (cnt[N_NODES + row] > 0)     v += b1[col];
                    if (cnt[2 * N_NODES + row] > 0) v += b2[col];
                    out[(size_t)row * D + col] = fmaxf(v, 0.0f);
                }
            }
        }
    }
}

extern "C" void kernel_launch(void* const* d_in, const int* in_sizes, int n_in,
                              void* d_out, int out_size, void* d_ws, size_t ws_size,
                              hipStream_t stream) {
    const float* feat = (const float*)d_in[0];
    const int* src0 = (const int*)d_in[1];
    const int* dst0 = (const int*)d_in[2];
    const int* src1 = (const int*)d_in[3];
    const int* dst1 = (const int*)d_in[4];
    const int* src2 = (const int*)d_in[5];
    const int* dst2 = (const int*)d_in[6];
    const float* W0 = (const float*)d_in[7];
    const float* b0 = (const float*)d_in[8];
    const float* W1 = (const float*)d_in[9];
    const float* b1 = (const float*)d_in[10];
    const float* W2 = (const float*)d_in[11];
    const float* b2 = (const float*)d_in[12];
    float* out = (float*)d_out;

    char* ws = (char*)d_ws;
    size_t o = 0;
    auto alloc = [&](size_t bytes) {
        size_t r = o;
        o += (bytes + 255) & ~(size_t)255;
        return r;
    };
    int* cnt            = (int*)(ws + alloc((size_t)SCAN_N * 4));
    int* off            = (int*)(ws + alloc((size_t)SCAN_N * 4));
    int* cur            = (int*)(ws + alloc((size_t)SCAN_N * 4));
    int* bsum           = (int*)(ws + alloc((size_t)SCAN_NBLK * 4));
    int* eidx           = (int*)(ws + alloc(3ull * N_EDGES * 4));
    unsigned short* WT  = (unsigned short*)(ws + alloc((size_t)D * K_TOT * 2));
    unsigned short* fb  = (unsigned short*)(ws + alloc((size_t)N_NODES * D * 2));
    unsigned short* agg = (unsigned short*)(ws + alloc(3ull * N_NODES * D * 2));

    hipMemsetAsync(cnt, 0, (size_t)SCAN_N * 4, stream);
    prep_kernel<<<(N_NODES * D / 4 + 255) / 256, 256, 0, stream>>>(
        feat, fb, W0, W1, W2, WT, dst0, dst1, dst2, cnt);
    scan1_kernel<<<SCAN_NBLK, 1024, 0, stream>>>(cnt, off, cur, bsum);
    scan2_kernel<<<1, 1024, 0, stream>>>(bsum);
    dim3 fg((3 * N_EDGES + 255) / 256, NPASS);
    fill_kernel<<<fg, 256, 0, stream>>>(src0, dst0, src1, dst1, src2, dst2, cur, bsum, eidx);
    agg_kernel<<<(N_NODES * 64 + 255) / 256, 256, 0, stream>>>(fb, off, cnt, bsum, eidx, agg);
    gemm_kernel<<<NMB, 512, 0, stream>>>(agg, WT, cnt, b0, b1, b2, out);
}

// Round 11
// 369.350 us; speedup vs baseline: 1.0212x; 1.0212x over previous
//
#include <hip/hip_runtime.h>
#include <hip/hip_bf16.h>

#define N_NODES 50000
#define N_EDGES 500000
#define D 256
#define K_TOT 768      // 3 * D
#define M_TILE 256
#define N_TILE 256
#define BK 32
#define NKT (K_TOT / BK)                     // 24
#define SCAN_N (3 * N_NODES)
#define SCAN_NBLK ((SCAN_N + 1023) / 1024)   // 147
#define NPASS 4                              // dst>>14: 50000 < 4*16384
#define NMB ((N_NODES + M_TILE - 1) / M_TILE)  // 196 blocks, single generation

typedef __attribute__((ext_vector_type(8))) __bf16 bf16x8;
typedef __attribute__((ext_vector_type(4))) float f32x4;
typedef __attribute__((ext_vector_type(4))) unsigned u32x4;

__device__ __forceinline__ unsigned short f2bf(float f) {
    unsigned u = __builtin_bit_cast(unsigned, f);
    u += 0x7FFFu + ((u >> 16) & 1u);   // round-to-nearest-even
    return (unsigned short)(u >> 16);
}
__device__ __forceinline__ float lo2f(unsigned u) {
    return __builtin_bit_cast(float, u << 16);
}
__device__ __forceinline__ float hi2f(unsigned u) {
    return __builtin_bit_cast(float, u & 0xFFFF0000u);
}
__device__ __forceinline__ void gload16(const unsigned short* g, __bf16* l) {
    __builtin_amdgcn_global_load_lds(
        (const __attribute__((address_space(1))) void*)g,
        (__attribute__((address_space(3))) void*)l, 16, 0, 0);
}

// ---------------- prep: feat->bf16 + W->bf16 transposed + edge COUNT (cnt pre-zeroed) ----------------
__global__ void prep_kernel(const float* __restrict__ feat, unsigned short* __restrict__ fb,
                            const float* __restrict__ W0, const float* __restrict__ W1,
                            const float* __restrict__ W2, unsigned short* __restrict__ WT,
                            const int* __restrict__ d0, const int* __restrict__ d1,
                            const int* __restrict__ d2, int* __restrict__ cnt) {
    int i = blockIdx.x * blockDim.x + threadIdx.x;
    if (i < N_NODES * D / 4) {                       // 3.2M float4 slots
        float4 v = ((const float4*)feat)[i];
        ushort4 pk;
        pk.x = f2bf(v.x); pk.y = f2bf(v.y); pk.z = f2bf(v.z); pk.w = f2bf(v.w);
        ((ushort4*)fb)[i] = pk;
    }
    if (i < D * K_TOT) {                             // WT[c][k], k = r*256+kin
        int c = i / K_TOT;
        int k = i - c * K_TOT;
        int r = k >> 8, kin = k & 255;
        const float* W = (r == 0) ? W0 : (r == 1) ? W1 : W2;
        WT[i] = f2bf(W[kin * D + c]);
    }
    if (i < 3 * N_EDGES) {                           // fused count (cnt zeroed by memset)
        int r = i / N_EDGES;
        int e = i - r * N_EDGES;
        const int* d = (r == 0) ? d0 : (r == 1) ? d1 : d2;
        atomicAdd(&cnt[r * N_NODES + d[e]], 1);
    }
}

// per-block exclusive scan; off/cur hold BLOCK-LOCAL offsets, bsum holds block totals
__global__ void scan1_kernel(const int* __restrict__ cnt, int* __restrict__ off,
                             int* __restrict__ cur, int* __restrict__ bsum) {
    __shared__ int wsum[16];
    int tid = threadIdx.x, lane = tid & 63, wid = tid >> 6;
    int i = blockIdx.x * 1024 + tid;
    int v = (i < SCAN_N) ? cnt[i] : 0;
    int x = v;
    #pragma unroll
    for (int d = 1; d < 64; d <<= 1) {
        int y = __shfl_up(x, d, 64);
        if (lane >= d) x += y;
    }
    if (lane == 63) wsum[wid] = x;
    __syncthreads();
    if (wid == 0 && lane < 16) {
        int s = wsum[lane];
        #pragma unroll
        for (int d = 1; d < 16; d <<= 1) {
            int y = __shfl_up(s, d, 64);
            if (lane >= d) s += y;
        }
        wsum[lane] = s;
    }
    __syncthreads();
    int wpre = wid ? wsum[wid - 1] : 0;
    int excl = x - v + wpre;
    if (i < SCAN_N) { off[i] = excl; cur[i] = excl; }
    if (tid == 1023) bsum[blockIdx.x] = x + wpre;
}

// exclusive scan of the 147 block sums (single block, in place)
__global__ void scan2_kernel(int* __restrict__ bsum) {
    __shared__ int wsum[16];
    int tid = threadIdx.x, lane = tid & 63, wid = tid >> 6;
    int v = (tid < SCAN_NBLK) ? bsum[tid] : 0;
    int x = v;
    #pragma unroll
    for (int d = 1; d < 64; d <<= 1) {
        int y = __shfl_up(x, d, 64);
        if (lane >= d) x += y;
    }
    if (lane == 63) wsum[wid] = x;
    __syncthreads();
    if (wid == 0 && lane < 16) {
        int s = wsum[lane];
        #pragma unroll
        for (int d = 1; d < 16; d <<= 1) {
            int y = __shfl_up(s, d, 64);
            if (lane >= d) s += y;
        }
        wsum[lane] = s;
    }
    __syncthreads();
    int wpre = wid ? wsum[wid - 1] : 0;
    if (tid < SCAN_NBLK) bsum[tid] = x - v + wpre;
}

// fill in NPASS dst-range passes (blockIdx.y = pass): confines the eidx scatter
// to ~2 MB hot window per pass so lines merge in L2 before eviction.
__global__ void fill_kernel(const int* __restrict__ s0, const int* __restrict__ d0,
                            const int* __restrict__ s1, const int* __restrict__ d1,
                            const int* __restrict__ s2, const int* __restrict__ d2,
                            int* __restrict__ cur, const int* __restrict__ bsum,
                            int* __restrict__ eidx) {
    int i = blockIdx.x * blockDim.x + threadIdx.x;
    if (i >= 3 * N_EDGES) return;
    int pass = blockIdx.y;
    int r = i / N_EDGES;
    int e = i - r * N_EDGES;
    const int* d = (r == 0) ? d0 : (r == 1) ? d1 : d2;
    int dd = d[e];
    if ((dd >> 14) != pass) return;
    const int* s = (r == 0) ? s0 : (r == 1) ? s1 : s2;
    int x = r * N_NODES + dd;
    int p = atomicAdd(&cur[x], 1) + bsum[x >> 10];
    eidx[p] = s[e];
}

// ---------------- per-(relation,node) mean aggregation, ONE RELATION PER DISPATCH ----------------
// Round-8 inner structure (paired 16B loads, 4-deep, low VGPR), single relation ->
// 3x the waves for TLP-overlap of VALU and memory. NT output store (not re-read
// until gemm, > L2) keeps fb resident in L2.
__global__ void agg_kernel(const unsigned short* __restrict__ fb, const int* __restrict__ off,
                           const int* __restrict__ cnt, const int* __restrict__ bsum,
                           const int* __restrict__ eidx, unsigned short* __restrict__ agg,
                           int r) {
    int n = (blockIdx.x * blockDim.x + threadIdx.x) >> 6;
    int lane = threadIdx.x & 63;
    if (n >= N_NODES) return;
    int half = lane >> 5, sub = lane & 31;
    const unsigned short* fbs = fb + sub * 8;

    int x = r * N_NODES + n;
    int st = off[x] + bsum[x >> 10];
    int deg = cnt[x];
    int dcap = min(deg, 64);
    int e = (lane < dcap) ? eidx[st + lane] : 0;

    float a0 = 0.f, a1 = 0.f, a2 = 0.f, a3 = 0.f, a4 = 0.f, a5 = 0.f, a6 = 0.f, a7 = 0.f;
    auto ACC = [&](uint4 v) {
        a0 += lo2f(v.x); a1 += hi2f(v.x);
        a2 += lo2f(v.y); a3 += hi2f(v.y);
        a4 += lo2f(v.z); a5 += hi2f(v.z);
        a6 += lo2f(v.w); a7 += hi2f(v.w);
    };
    int j = 0;
    for (; j + 8 <= dcap; j += 8) {               // 4 independent 16B loads in flight
        int t0 = __shfl(e, j + 0 + half);
        int t1 = __shfl(e, j + 2 + half);
        int t2 = __shfl(e, j + 4 + half);
        int t3 = __shfl(e, j + 6 + half);
        uint4 v0 = *(const uint4*)(fbs + (size_t)t0 * D);
        uint4 v1 = *(const uint4*)(fbs + (size_t)t1 * D);
        uint4 v2 = *(const uint4*)(fbs + (size_t)t2 * D);
        uint4 v3 = *(const uint4*)(fbs + (size_t)t3 * D);
        ACC(v0); ACC(v1); ACC(v2); ACC(v3);
    }
    for (; j < dcap; j += 2) {                    // tail pairs (validity-predicated)
        int idx = j + half;
        int t = __shfl(e, idx < dcap ? idx : dcap - 1);
        uint4 v = *(const uint4*)(fbs + (size_t)t * D);
        if (idx >= dcap) { v.x = 0u; v.y = 0u; v.z = 0u; v.w = 0u; }
        ACC(v);
    }
    if (deg > 64) {                               // safety fallback (P~0 for this input)
        for (int ei = 64; ei < deg; ++ei) {
            int t = eidx[st + ei];
            uint4 v = *(const uint4*)(fbs + (size_t)t * D);
            if (half) { v.x = 0u; v.y = 0u; v.z = 0u; v.w = 0u; }
            ACC(v);
        }
    }

    float t0 = a0 + __shfl_xor(a0, 32), t1 = a1 + __shfl_xor(a1, 32);
    float t2 = a2 + __shfl_xor(a2, 32), t3 = a3 + __shfl_xor(a3, 32);
    float t4 = a4 + __shfl_xor(a4, 32), t5 = a5 + __shfl_xor(a5, 32);
    float t6 = a6 + __shfl_xor(a6, 32), t7 = a7 + __shfl_xor(a7, 32);
    float sc = (deg > 0) ? 1.0f / (float)deg : 0.0f;
    if (half == 0) {                              // 32 lanes x 16 B = 512 B row
        u32x4 pk;
        pk.x = (unsigned)f2bf(t0 * sc) | ((unsigned)f2bf(t1 * sc) << 16);
        pk.y = (unsigned)f2bf(t2 * sc) | ((unsigned)f2bf(t3 * sc) << 16);
        pk.z = (unsigned)f2bf(t4 * sc) | ((unsigned)f2bf(t5 * sc) << 16);
        pk.w = (unsigned)f2bf(t6 * sc) | ((unsigned)f2bf(t7 * sc) << 16);
        __builtin_nontemporal_store(pk, (u32x4*)(agg + ((size_t)n * 3 + r) * D + sub * 8));
    }
}

// ---------------- fused GEMM: out = relu( A[50000][768] @ B[768][256] + masked biases ) ----------------
// SINGLE-GENERATION design: 256x256 tiles, 512 threads (8 waves, 2x4), grid = 196
// blocks < 256 CUs -> all blocks concurrent; per-K-step drain costs amortize.
// 3-buffer LDS (96 KB), unrolled K-loop, counted vmcnt; swizzle seg^((row>>1)&3).
__global__ __launch_bounds__(512) void gemm_kernel(
    const unsigned short* __restrict__ A, const unsigned short* __restrict__ BT,
    const int* __restrict__ cnt,
    const float* __restrict__ b0, const float* __restrict__ b1, const float* __restrict__ b2,
    float* __restrict__ out) {
    __shared__ __bf16 Asl[3][M_TILE][BK];   // 3 x 16 KB
    __shared__ __bf16 Bsl[3][N_TILE][BK];   // 3 x 16 KB
    int tid = threadIdx.x;
    int lane = tid & 63, w = tid >> 6;      // 8 waves
    int wr = w >> 2, wc = w & 3;            // wave tile: 128 rows x 64 cols
    int m0 = blockIdx.x * M_TILE;
    f32x4 acc[8][4] = {};

    // staging geometry: A tile = 1024 16B slots, B tile = 1024; thread does 2+2
    int s_lo = tid;                                      // slot 0..511
    int row_lo = s_lo >> 2, row_hi = (s_lo + 512) >> 2;
    int seg_lo = (s_lo & 3) ^ ((row_lo >> 1) & 3);       // inverse-swizzled global seg
    int seg_hi = (s_lo & 3) ^ ((row_hi >> 1) & 3);
    int gma = m0 + row_lo; if (gma >= N_NODES) gma = N_NODES - 1;
    int gmb = m0 + row_hi; if (gmb >= N_NODES) gmb = N_NODES - 1;
    const unsigned short* ga_lo = A + (size_t)gma * K_TOT + seg_lo * 8;
    const unsigned short* ga_hi = A + (size_t)gmb * K_TOT + seg_hi * 8;
    const unsigned short* gb_lo = BT + (size_t)row_lo * K_TOT + seg_lo * 8;
    const unsigned short* gb_hi = BT + (size_t)row_hi * K_TOT + seg_hi * 8;

    auto stage = [&](int kt, int b) {                    // b compile-time after unroll
        gload16(ga_lo + kt * BK, &Asl[b][0][0] + (size_t)s_lo * 8);
        gload16(ga_hi + kt * BK, &Asl[b][0][0] + (size_t)(s_lo + 512) * 8);
        gload16(gb_lo + kt * BK, &Bsl[b][0][0] + (size_t)s_lo * 8);
        gload16(gb_hi + kt * BK, &Bsl[b][0][0] + (size_t)(s_lo + 512) * 8);
    };

    stage(0, 0);
    stage(1, 1);
    int q = lane >> 4;
    int rr = lane & 15;
    #pragma unroll
    for (int kt = 0; kt < NKT; ++kt) {
        if (kt + 1 < NKT) asm volatile("s_waitcnt vmcnt(4)" ::: "memory");
        else              asm volatile("s_waitcnt vmcnt(0)" ::: "memory");
        __builtin_amdgcn_s_barrier();
        int b = kt % 3;
        bf16x8 af[8], bfr[4];
        #pragma unroll
        for (int mf = 0; mf < 8; ++mf) {
            int row = wr * 128 + mf * 16 + rr;
            af[mf] = *(const bf16x8*)&Asl[b][row][(q ^ ((row >> 1) & 3)) * 8];
        }
        #pragma unroll
        for (int nf = 0; nf < 4; ++nf) {
            int row = wc * 64 + nf * 16 + rr;
            bfr[nf] = *(const bf16x8*)&Bsl[b][row][(q ^ ((row >> 1) & 3)) * 8];
        }
        if (kt + 2 < NKT) stage(kt + 2, (kt + 2) % 3);
        #pragma unroll
        for (int mf = 0; mf < 8; ++mf)
            #pragma unroll
            for (int nf = 0; nf < 4; ++nf)
                acc[mf][nf] = __builtin_amdgcn_mfma_f32_16x16x32_bf16(af[mf], bfr[nf], acc[mf][nf], 0, 0, 0);
    }

    // epilogue: masked biases + relu; C/D layout: col = lane&15, row = (lane>>4)*4 + reg
    #pragma unroll
    for (int mf = 0; mf < 8; ++mf) {
        #pragma unroll
        for (int nf = 0; nf < 4; ++nf) {
            int col = wc * 64 + nf * 16 + rr;            // global col (N_TILE == D)
            #pragma unroll
            for (int reg = 0; reg < 4; ++reg) {
                int row = m0 + wr * 128 + mf * 16 + q * 4 + reg;
                if (row < N_NODES) {
                    float v = acc[mf][nf][reg];
                    if (cnt[row] > 0)               v += b0[col];
                    if (cnt[N_NODES + row] > 0)     v += b1[col];
                    if (cnt[2 * N_NODES + row] > 0) v += b2[col];
                    __builtin_nontemporal_store(fmaxf(v, 0.0f), &out[(size_t)row * D + col]);
                }
            }
        }
    }
}

extern "C" void kernel_launch(void* const* d_in, const int* in_sizes, int n_in,
                              void* d_out, int out_size, void* d_ws, size_t ws_size,
                              hipStream_t stream) {
    const float* feat = (const float*)d_in[0];
    const int* src0 = (const int*)d_in[1];
    const int* dst0 = (const int*)d_in[2];
    const int* src1 = (const int*)d_in[3];
    const int* dst1 = (const int*)d_in[4];
    const int* src2 = (const int*)d_in[5];
    const int* dst2 = (const int*)d_in[6];
    const float* W0 = (const float*)d_in[7];
    const float* b0 = (const float*)d_in[8];
    const float* W1 = (const float*)d_in[9];
    const float* b1 = (const float*)d_in[10];
    const float* W2 = (const float*)d_in[11];
    const float* b2 = (const float*)d_in[12];
    float* out = (float*)d_out;

    char* ws = (char*)d_ws;
    size_t o = 0;
    auto alloc = [&](size_t bytes) {
        size_t r = o;
        o += (bytes + 255) & ~(size_t)255;
        return r;
    };
    int* cnt            = (int*)(ws + alloc((size_t)SCAN_N * 4));
    int* off            = (int*)(ws + alloc((size_t)SCAN_N * 4));
    int* cur            = (int*)(ws + alloc((size_t)SCAN_N * 4));
    int* bsum           = (int*)(ws + alloc((size_t)SCAN_NBLK * 4));
    int* eidx           = (int*)(ws + alloc(3ull * N_EDGES * 4));
    unsigned short* WT  = (unsigned short*)(ws + alloc((size_t)D * K_TOT * 2));
    unsigned short* fb  = (unsigned short*)(ws + alloc((size_t)N_NODES * D * 2));
    unsigned short* agg = (unsigned short*)(ws + alloc(3ull * N_NODES * D * 2));

    (void)hipMemsetAsync(cnt, 0, (size_t)SCAN_N * 4, stream);
    prep_kernel<<<(N_NODES * D / 4 + 255) / 256, 256, 0, stream>>>(
        feat, fb, W0, W1, W2, WT, dst0, dst1, dst2, cnt);
    scan1_kernel<<<SCAN_NBLK, 1024, 0, stream>>>(cnt, off, cur, bsum);
    scan2_kernel<<<1, 1024, 0, stream>>>(bsum);
    dim3 fg((3 * N_EDGES + 255) / 256, NPASS);
    fill_kernel<<<fg, 256, 0, stream>>>(src0, dst0, src1, dst1, src2, dst2, cur, bsum, eidx);
    int ablk = (N_NODES * 64 + 255) / 256;
    agg_kernel<<<ablk, 256, 0, stream>>>(fb, off, cnt, bsum, eidx, agg, 0);
    agg_kernel<<<ablk, 256, 0, stream>>>(fb, off, cnt, bsum, eidx, agg, 1);
    agg_kernel<<<ablk, 256, 0, stream>>>(fb, off, cnt, bsum, eidx, agg, 2);
    gemm_kernel<<<NMB, 512, 0, stream>>>(agg, WT, cnt, b0, b1, b2, out);
}

// Round 12
// 324.587 us; speedup vs baseline: 1.1621x; 1.1379x over previous
//
#include <hip/hip_runtime.h>
#include <hip/hip_bf16.h>

#define N_NODES 50000
#define N_EDGES 500000
#define D 256
#define N_TOT 768      // 3 * D output cols of Wh
#define SCAN_N (3 * N_NODES)
#define SCAN_NBLK ((SCAN_N + 1023) / 1024)   // 147
#define NPASS 4                              // dst>>14: 50000 < 4*16384
#define NMB ((N_NODES + 255) / 256)          // 196 M-blocks

typedef __attribute__((ext_vector_type(8))) __bf16 bf16x8;
typedef __attribute__((ext_vector_type(4))) float f32x4;

__device__ __forceinline__ unsigned short f2bf(float f) {
    unsigned u = __builtin_bit_cast(unsigned, f);
    u += 0x7FFFu + ((u >> 16) & 1u);   // round-to-nearest-even
    return (unsigned short)(u >> 16);
}
__device__ __forceinline__ float bf2f(unsigned short h) {
    return __builtin_bit_cast(float, (unsigned)h << 16);
}
__device__ __forceinline__ void gload16(const unsigned short* g, __bf16* l) {
    __builtin_amdgcn_global_load_lds(
        (const __attribute__((address_space(1))) void*)g,
        (__attribute__((address_space(3))) void*)l, 16, 0, 0);
}

// ---------------- prep: feat->bf16 + W->bf16 transposed + edge COUNT (cnt pre-zeroed) ----------------
// WT layout: [768 outcols j=r*256+c][256 k], WT[j][k] = W_r[k][c]
__global__ void prep_kernel(const float* __restrict__ feat, unsigned short* __restrict__ fb,
                            const float* __restrict__ W0, const float* __restrict__ W1,
                            const float* __restrict__ W2, unsigned short* __restrict__ WT,
                            const int* __restrict__ d0, const int* __restrict__ d1,
                            const int* __restrict__ d2, int* __restrict__ cnt) {
    int i = blockIdx.x * blockDim.x + threadIdx.x;
    if (i < N_NODES * D / 4) {                       // 3.2M float4 slots
        float4 v = ((const float4*)feat)[i];
        ushort4 pk;
        pk.x = f2bf(v.x); pk.y = f2bf(v.y); pk.z = f2bf(v.z); pk.w = f2bf(v.w);
        ((ushort4*)fb)[i] = pk;
    }
    if (i < N_TOT * D) {                             // 196608
        int j = i >> 8, k = i & 255;
        int r = j >> 8, c = j & 255;
        const float* W = (r == 0) ? W0 : (r == 1) ? W1 : W2;
        WT[i] = f2bf(W[k * D + c]);
    }
    if (i < 3 * N_EDGES) {                           // fused count (cnt zeroed by memset)
        int r = i / N_EDGES;
        int e = i - r * N_EDGES;
        const int* d = (r == 0) ? d0 : (r == 1) ? d1 : d2;
        atomicAdd(&cnt[r * N_NODES + d[e]], 1);
    }
}

// per-block exclusive scan; off/cur hold BLOCK-LOCAL offsets, bsum holds block totals
__global__ void scan1_kernel(const int* __restrict__ cnt, int* __restrict__ off,
                             int* __restrict__ cur, int* __restrict__ bsum) {
    __shared__ int wsum[16];
    int tid = threadIdx.x, lane = tid & 63, wid = tid >> 6;
    int i = blockIdx.x * 1024 + tid;
    int v = (i < SCAN_N) ? cnt[i] : 0;
    int x = v;
    #pragma unroll
    for (int d = 1; d < 64; d <<= 1) {
        int y = __shfl_up(x, d, 64);
        if (lane >= d) x += y;
    }
    if (lane == 63) wsum[wid] = x;
    __syncthreads();
    if (wid == 0 && lane < 16) {
        int s = wsum[lane];
        #pragma unroll
        for (int d = 1; d < 16; d <<= 1) {
            int y = __shfl_up(s, d, 64);
            if (lane >= d) s += y;
        }
        wsum[lane] = s;
    }
    __syncthreads();
    int wpre = wid ? wsum[wid - 1] : 0;
    int excl = x - v + wpre;
    if (i < SCAN_N) { off[i] = excl; cur[i] = excl; }
    if (tid == 1023) bsum[blockIdx.x] = x + wpre;
}

// exclusive scan of the 147 block sums (single block, in place)
__global__ void scan2_kernel(int* __restrict__ bsum) {
    __shared__ int wsum[16];
    int tid = threadIdx.x, lane = tid & 63, wid = tid >> 6;
    int v = (tid < SCAN_NBLK) ? bsum[tid] : 0;
    int x = v;
    #pragma unroll
    for (int d = 1; d < 64; d <<= 1) {
        int y = __shfl_up(x, d, 64);
        if (lane >= d) x += y;
    }
    if (lane == 63) wsum[wid] = x;
    __syncthreads();
    if (wid == 0 && lane < 16) {
        int s = wsum[lane];
        #pragma unroll
        for (int d = 1; d < 16; d <<= 1) {
            int y = __shfl_up(s, d, 64);
            if (lane >= d) s += y;
        }
        wsum[lane] = s;
    }
    __syncthreads();
    int wpre = wid ? wsum[wid - 1] : 0;
    if (tid < SCAN_NBLK) bsum[tid] = x - v + wpre;
}

// fill in NPASS dst-range passes (blockIdx.y = pass)
__global__ void fill_kernel(const int* __restrict__ s0, const int* __restrict__ d0,
                            const int* __restrict__ s1, const int* __restrict__ d1,
                            const int* __restrict__ s2, const int* __restrict__ d2,
                            int* __restrict__ cur, const int* __restrict__ bsum,
                            int* __restrict__ eidx) {
    int i = blockIdx.x * blockDim.x + threadIdx.x;
    if (i >= 3 * N_EDGES) return;
    int pass = blockIdx.y;
    int r = i / N_EDGES;
    int e = i - r * N_EDGES;
    const int* d = (r == 0) ? d0 : (r == 1) ? d1 : d2;
    int dd = d[e];
    if ((dd >> 14) != pass) return;
    const int* s = (r == 0) ? s0 : (r == 1) ? s1 : s2;
    int x = r * N_NODES + dd;
    int p = atomicAdd(&cur[x], 1) + bsum[x >> 10];
    eidx[p] = s[e];
}

// ---------------- GEMM-FIRST: Wh[n][r*256+c] = bf16( feat[n] @ W_r + b_r ) ----------------
// K = 256 -> only 4 K-steps of BK=64 (per-step drain cost is the empirical bottleneck).
// 2-buffer LDS (128 KB), fully unrolled; swizzle slot^(row&7) both sides (linear LDS
// dest for global_load_lds + pre-swizzled global src + swizzled ds_read).
__global__ __launch_bounds__(512) void gemm_kernel(
    const unsigned short* __restrict__ A, const unsigned short* __restrict__ BT,
    const float* __restrict__ b0, const float* __restrict__ b1, const float* __restrict__ b2,
    unsigned short* __restrict__ Wh) {
    __shared__ __bf16 Asl[2][256][64];   // 2 x 32 KB
    __shared__ __bf16 Bsl[2][256][64];   // 2 x 32 KB
    int tid = threadIdx.x;
    int lane = tid & 63, w = tid >> 6;   // 8 waves
    int wr = w >> 2, wc = w & 3;         // wave tile: 128 rows x 64 cols
    int m0 = blockIdx.x * 256;
    int p = blockIdx.y;                  // relation panel 0..2
    const float* bp = (p == 0) ? b0 : (p == 1) ? b1 : b2;
    f32x4 acc[8][4] = {};

    auto stage = [&](int kt, int b) {
        #pragma unroll
        for (int i = 0; i < 4; ++i) {
            int slot = i * 512 + w * 64 + lane;        // 16B slots, wave-contiguous LDS
            int row = slot >> 3, ks = slot & 7;
            int g = ks ^ (row & 7);                    // pre-swizzled global k-slot
            int gm = m0 + row; if (gm >= N_NODES) gm = N_NODES - 1;
            gload16(A + (size_t)gm * D + kt * 64 + g * 8,
                    &Asl[b][0][0] + (size_t)slot * 8);
            gload16(BT + (size_t)(p * 256 + row) * D + kt * 64 + g * 8,
                    &Bsl[b][0][0] + (size_t)slot * 8);
        }
    };

    stage(0, 0);
    int rr = lane & 15, q = lane >> 4;
    #pragma unroll
    for (int kt = 0; kt < 4; ++kt) {
        asm volatile("s_waitcnt vmcnt(0)" ::: "memory");   // buf kt loads landed
        __builtin_amdgcn_s_barrier();
        int b = kt & 1;
        if (kt + 1 < 4) stage(kt + 1, b ^ 1);              // hide under compute below
        #pragma unroll
        for (int kh = 0; kh < 2; ++kh) {                   // two k-halves of BK=64
            bf16x8 af[8], bfr[4];
            #pragma unroll
            for (int mf = 0; mf < 8; ++mf) {
                int row = wr * 128 + mf * 16 + rr;
                int sl = (kh * 4 + q) ^ (row & 7);
                af[mf] = *(const bf16x8*)(&Asl[b][row][0] + sl * 8);
            }
            #pragma unroll
            for (int nf = 0; nf < 4; ++nf) {
                int row = wc * 64 + nf * 16 + rr;
                int sl = (kh * 4 + q) ^ (row & 7);
                bfr[nf] = *(const bf16x8*)(&Bsl[b][row][0] + sl * 8);
            }
            #pragma unroll
            for (int mf = 0; mf < 8; ++mf)
                #pragma unroll
                for (int nf = 0; nf < 4; ++nf)
                    acc[mf][nf] = __builtin_amdgcn_mfma_f32_16x16x32_bf16(af[mf], bfr[nf], acc[mf][nf], 0, 0, 0);
        }
        __builtin_amdgcn_s_barrier();                      // done reading buf b
    }

    // epilogue: +bias, cast bf16; C/D layout: col = lane&15, row = (lane>>4)*4 + reg
    #pragma unroll
    for (int mf = 0; mf < 8; ++mf) {
        #pragma unroll
        for (int nf = 0; nf < 4; ++nf) {
            int col = wc * 64 + nf * 16 + rr;
            float bb = bp[col];
            #pragma unroll
            for (int reg = 0; reg < 4; ++reg) {
                int row = m0 + wr * 128 + mf * 16 + q * 4 + reg;
                if (row < N_NODES)
                    Wh[(size_t)row * N_TOT + p * 256 + col] = f2bf(acc[mf][nf][reg] + bb);
            }
        }
    }
}

// ---------------- final: per-node gather Wh, mean per relation, sum, relu -> out (f32) ----------------
// One wave per node, all 3 relations; lane owns 4 channels (8B loads); 8-deep
// independent gathers (round-7 structure, measured 106 us). Bias is already inside
// Wh, so deg=0 relations contribute exactly 0 -- no masking needed.
__global__ void agg_kernel(const unsigned short* __restrict__ Wh, const int* __restrict__ off,
                           const int* __restrict__ cnt, const int* __restrict__ bsum,
                           const int* __restrict__ eidx, float* __restrict__ out) {
    int n = (blockIdx.x * blockDim.x + threadIdx.x) >> 6;
    int lane = threadIdx.x & 63;
    if (n >= N_NODES) return;

    int st3[3], dg3[3], e3[3];
    #pragma unroll
    for (int r = 0; r < 3; ++r) {
        int x = r * N_NODES + n;
        st3[r] = off[x] + bsum[x >> 10];
        dg3[r] = cnt[x];
    }
    #pragma unroll
    for (int r = 0; r < 3; ++r)                       // 3 head-loads in flight together
        e3[r] = (lane < dg3[r]) ? eidx[st3[r] + lane] : 0;

    float o0 = 0.f, o1 = 0.f, o2 = 0.f, o3 = 0.f;
    #pragma unroll
    for (int r = 0; r < 3; ++r) {
        const unsigned short* whl = Wh + r * 256 + lane * 4;
        int deg = dg3[r], start = st3[r];
        float4 acc = make_float4(0.f, 0.f, 0.f, 0.f);
        for (int base = 0; base < deg; base += 64) {
            int m = min(deg - base, 64);
            int e = base ? ((lane < m) ? eidx[start + base + lane] : 0) : e3[r];
            int j = 0;
            for (; j + 7 < m; j += 8) {
                int t0 = __shfl(e, j + 0), t1 = __shfl(e, j + 1), t2 = __shfl(e, j + 2), t3 = __shfl(e, j + 3);
                int t4 = __shfl(e, j + 4), t5 = __shfl(e, j + 5), t6 = __shfl(e, j + 6), t7 = __shfl(e, j + 7);
                ushort4 v0 = *(const ushort4*)(whl + (size_t)t0 * N_TOT);
                ushort4 v1 = *(const ushort4*)(whl + (size_t)t1 * N_TOT);
                ushort4 v2 = *(const ushort4*)(whl + (size_t)t2 * N_TOT);
                ushort4 v3 = *(const ushort4*)(whl + (size_t)t3 * N_TOT);
                ushort4 v4 = *(const ushort4*)(whl + (size_t)t4 * N_TOT);
                ushort4 v5 = *(const ushort4*)(whl + (size_t)t5 * N_TOT);
                ushort4 v6 = *(const ushort4*)(whl + (size_t)t6 * N_TOT);
                ushort4 v7 = *(const ushort4*)(whl + (size_t)t7 * N_TOT);
                acc.x += ((bf2f(v0.x) + bf2f(v1.x)) + (bf2f(v2.x) + bf2f(v3.x))) + ((bf2f(v4.x) + bf2f(v5.x)) + (bf2f(v6.x) + bf2f(v7.x)));
                acc.y += ((bf2f(v0.y) + bf2f(v1.y)) + (bf2f(v2.y) + bf2f(v3.y))) + ((bf2f(v4.y) + bf2f(v5.y)) + (bf2f(v6.y) + bf2f(v7.y)));
                acc.z += ((bf2f(v0.z) + bf2f(v1.z)) + (bf2f(v2.z) + bf2f(v3.z))) + ((bf2f(v4.z) + bf2f(v5.z)) + (bf2f(v6.z) + bf2f(v7.z)));
                acc.w += ((bf2f(v0.w) + bf2f(v1.w)) + (bf2f(v2.w) + bf2f(v3.w))) + ((bf2f(v4.w) + bf2f(v5.w)) + (bf2f(v6.w) + bf2f(v7.w)));
            }
            for (; j < m; ++j) {
                int t = __shfl(e, j);
                ushort4 v = *(const ushort4*)(whl + (size_t)t * N_TOT);
                acc.x += bf2f(v.x); acc.y += bf2f(v.y); acc.z += bf2f(v.z); acc.w += bf2f(v.w);
            }
        }
        float sc = (deg > 0) ? 1.0f / (float)deg : 0.0f;
        o0 += acc.x * sc; o1 += acc.y * sc; o2 += acc.z * sc; o3 += acc.w * sc;
    }
    f32x4 o;
    o.x = fmaxf(o0, 0.0f); o.y = fmaxf(o1, 0.0f);
    o.z = fmaxf(o2, 0.0f); o.w = fmaxf(o3, 0.0f);
    __builtin_nontemporal_store(o, (f32x4*)(out + (size_t)n * D + lane * 4));
}

extern "C" void kernel_launch(void* const* d_in, const int* in_sizes, int n_in,
                              void* d_out, int out_size, void* d_ws, size_t ws_size,
                              hipStream_t stream) {
    const float* feat = (const float*)d_in[0];
    const int* src0 = (const int*)d_in[1];
    const int* dst0 = (const int*)d_in[2];
    const int* src1 = (const int*)d_in[3];
    const int* dst1 = (const int*)d_in[4];
    const int* src2 = (const int*)d_in[5];
    const int* dst2 = (const int*)d_in[6];
    const float* W0 = (const float*)d_in[7];
    const float* b0 = (const float*)d_in[8];
    const float* W1 = (const float*)d_in[9];
    const float* b1 = (const float*)d_in[10];
    const float* W2 = (const float*)d_in[11];
    const float* b2 = (const float*)d_in[12];
    float* out = (float*)d_out;

    char* ws = (char*)d_ws;
    size_t o = 0;
    auto alloc = [&](size_t bytes) {
        size_t r = o;
        o += (bytes + 255) & ~(size_t)255;
        return r;
    };
    int* cnt            = (int*)(ws + alloc((size_t)SCAN_N * 4));
    int* off            = (int*)(ws + alloc((size_t)SCAN_N * 4));
    int* cur            = (int*)(ws + alloc((size_t)SCAN_N * 4));
    int* bsum           = (int*)(ws + alloc((size_t)SCAN_NBLK * 4));
    int* eidx           = (int*)(ws + alloc(3ull * N_EDGES * 4));
    unsigned short* WT  = (unsigned short*)(ws + alloc((size_t)N_TOT * D * 2));
    unsigned short* fb  = (unsigned short*)(ws + alloc((size_t)N_NODES * D * 2));
    unsigned short* Wh  = (unsigned short*)(ws + alloc((size_t)N_NODES * N_TOT * 2));

    (void)hipMemsetAsync(cnt, 0, (size_t)SCAN_N * 4, stream);
    prep_kernel<<<(N_NODES * D / 4 + 255) / 256, 256, 0, stream>>>(
        feat, fb, W0, W1, W2, WT, dst0, dst1, dst2, cnt);
    dim3 gg(NMB, 3);
    gemm_kernel<<<gg, 512, 0, stream>>>(fb, WT, b0, b1, b2, Wh);
    scan1_kernel<<<SCAN_NBLK, 1024, 0, stream>>>(cnt, off, cur, bsum);
    scan2_kernel<<<1, 1024, 0, stream>>>(bsum);
    dim3 fg((3 * N_EDGES + 255) / 256, NPASS);
    fill_kernel<<<fg, 256, 0, stream>>>(src0, dst0, src1, dst1, src2, dst2, cur, bsum, eidx);
    agg_kernel<<<(N_NODES * 64 + 255) / 256, 256, 0, stream>>>(Wh, off, cnt, bsum, eidx, out);
}